// Round 6
// baseline (4326.480 us; speedup 1.0000x reference)
//
#include <hip/hip_runtime.h>
#include <math.h>

#define N_FEAT 8192
#define DIM    768
#define B_H    4096
#define P_PK   2048
#define C_CLS  256
#define KNN    20
#define MCAND  32   // candidate margin for exact re-rank

// output layout (all float32, concatenated in reference return order)
#define OUT_DENS_OFF  (B_H * C_CLS)                 // 1048576
#define OUT_KNN_OFF   (OUT_DENS_OFF + N_FEAT)       // 1056768
#define OUT_MASK_OFF  (OUT_KNN_OFF + N_FEAT * KNN)  // 1220608

// ---------------------------------------------------------------------------
// Truth-rounded f32 row norm: n32 = fl32( sqrt_f64( sum_f64(x^2) ) ).
// One wave per row. Also emits 1/n32 for the fast candidate GEMM.
// ---------------------------------------------------------------------------
__global__ __launch_bounds__(256) void norm64_kernel(const float* __restrict__ X,
    float* __restrict__ nrm, float* __restrict__ rn, int rows) {
  int w    = (int)((blockIdx.x * blockDim.x + threadIdx.x) >> 6);
  int lane = threadIdx.x & 63;
  if (w >= rows) return;
  const float* x = X + (size_t)w * DIM;
  double s = 0.0;
#pragma unroll
  for (int k = 0; k < 12; ++k) {
    float v = x[lane + 64 * k];
    s += (double)v * (double)v;
  }
#pragma unroll
  for (int off = 32; off; off >>= 1) s += __shfl_xor(s, off);
  if (lane == 0) {
    float n32 = (float)sqrt(s);          // truth-rounded f32 norm
    nrm[w] = n32;
    rn[w]  = 1.0f / n32;
  }
}

// ---------------------------------------------------------------------------
// Fast f32 candidate GEMM with streaming top-MCAND list (self excluded).
// Candidates only; exact ranking happens in refine. (unchanged since r1)
// ---------------------------------------------------------------------------
__global__ __launch_bounds__(512) void sim_topk_kernel(const float* __restrict__ F,
    const float* __restrict__ rn, int* __restrict__ cand) {
  __shared__ __align__(16) float As[32][36];
  __shared__ __align__(16) float Bs[32][132];
  __shared__ __align__(16) float simb[32][130];
  __shared__ float topv[32][MCAND];
  __shared__ int   topi[32][MCAND];

  const int t  = threadIdx.x;
  const int ib = blockIdx.x * 32;
  const int tx = t & 63;
  const int ry = t >> 6;
  const int ar  = t >> 4;
  const int akk = (t & 15) * 2;
  const int br  = t >> 2;
  const int bkk = (t & 3) * 8;

  for (int i = t; i < 32 * MCAND; i += 512) {
    ((float*)topv)[i] = -1e30f;
    ((int*)topi)[i]   = 0;
  }
  const float arn = rn[ib + ar];
  __syncthreads();

  for (int ct = 0; ct < 64; ++ct) {
    const int jb = ct * 128;
    const float brn = rn[jb + br];
    float acc[4][2];
#pragma unroll
    for (int r = 0; r < 4; ++r) { acc[r][0] = 0.f; acc[r][1] = 0.f; }

    for (int kc = 0; kc < 24; ++kc) {
      const int kb = kc * 32;
      __syncthreads();
      {
        float2 v = *(const float2*)(F + (size_t)(ib + ar) * DIM + kb + akk);
        As[akk][ar]     = v.x * arn;
        As[akk + 1][ar] = v.y * arn;
      }
      {
        const float* src = F + (size_t)(jb + br) * DIM + kb + bkk;
        float4 v0 = *(const float4*)(src);
        float4 v1 = *(const float4*)(src + 4);
        Bs[bkk + 0][br] = v0.x * brn;
        Bs[bkk + 1][br] = v0.y * brn;
        Bs[bkk + 2][br] = v0.z * brn;
        Bs[bkk + 3][br] = v0.w * brn;
        Bs[bkk + 4][br] = v1.x * brn;
        Bs[bkk + 5][br] = v1.y * brn;
        Bs[bkk + 6][br] = v1.z * brn;
        Bs[bkk + 7][br] = v1.w * brn;
      }
      __syncthreads();
#pragma unroll
      for (int k = 0; k < 32; ++k) {
        float4 a = *(const float4*)&As[k][4 * ry];
        float2 b = *(const float2*)&Bs[k][2 * tx];
        acc[0][0] += a.x * b.x; acc[0][1] += a.x * b.y;
        acc[1][0] += a.y * b.x; acc[1][1] += a.y * b.y;
        acc[2][0] += a.z * b.x; acc[2][1] += a.z * b.y;
        acc[3][0] += a.w * b.x; acc[3][1] += a.w * b.y;
      }
    }
#pragma unroll
    for (int r = 0; r < 4; ++r) {
      *(float2*)&simb[4 * ry + r][2 * tx] = make_float2(acc[r][0], acc[r][1]);
    }
    for (int rr = 0; rr < 4; ++rr) {
      const int r  = 4 * ry + rr;
      const int ig = ib + r;
      float v0 = simb[r][tx];
      float v1 = simb[r][64 + tx];
      if (jb + tx == ig)      v0 = -3.0e38f;
      if (jb + 64 + tx == ig) v1 = -3.0e38f;
      float cmin = topv[r][MCAND - 1];
      unsigned long long m0 = __ballot(v0 > cmin);
      unsigned long long m1 = __ballot(v1 > cmin);
      while (m0 | m1) {
        float v; int j;
        if (m0) {
          int l = __ffsll(m0) - 1; m0 &= (m0 - 1);
          v = __shfl(v0, l); j = jb + l;
        } else {
          int l = __ffsll(m1) - 1; m1 &= (m1 - 1);
          v = __shfl(v1, l); j = jb + 64 + l;
        }
        if (v > topv[r][MCAND - 1]) {
          int pos = MCAND - 1;
          while (pos > 0 && topv[r][pos - 1] < v) {
            topv[r][pos] = topv[r][pos - 1];
            topi[r][pos] = topi[r][pos - 1];
            --pos;
          }
          topv[r][pos] = v;
          topi[r][pos] = j;
        }
      }
    }
  }
  for (int rr = 0; rr < 4; ++rr) {
    const int r  = 4 * ry + rr;
    const int ig = ib + r;
    if (tx < MCAND) cand[(size_t)ig * MCAND + tx] = topi[r][tx];
  }
}

// ---------------------------------------------------------------------------
// Re-rank by fl32(truth): fn = fl32(F/n32) (materialized-f32 fn like ref),
// dot accumulated in f64 (f32xf32 exact), rounded to f32 at the end.
// Ties in f32 broken HIGH-index-first (reversed-argsort shim semantics).
// One block = 8 rows x 32 candidate-threads; each thread = one full dot.
// ---------------------------------------------------------------------------
__global__ __launch_bounds__(256) void refine_kernel(const float* __restrict__ F,
    const float* __restrict__ nrm, const int* __restrict__ cand,
    float* __restrict__ dens, float* __restrict__ knnf) {
#pragma clang fp contract(off)
  const int t  = threadIdx.x;
  const int i0 = blockIdx.x * 8;
  __shared__ __align__(16) float fni[8][DIM];   // 24 KB
  __shared__ float svals[8][MCAND];
  __shared__ int   sidx[8][MCAND];
  __shared__ float ssorted[8][MCAND];

  // stage fn_i rows: bit-exact f32 division by the truth-rounded f32 norm
  for (int r = 0; r < 8; ++r) {
    const float ni = nrm[i0 + r];
    const float* src = F + (size_t)(i0 + r) * DIM;
    for (int d = t; d < DIM; d += 256) fni[r][d] = src[d] / ni;
  }
  __syncthreads();

  const int row = t >> 5;       // 0..7
  const int c   = t & 31;       // candidate slot
  const int ig  = i0 + row;
  const int j   = cand[(size_t)ig * MCAND + c];
  const float nj = nrm[j];
  const float* fj = F + (size_t)j * DIM;
  const float* a  = fni[row];

  double acc = 0.0;
#pragma unroll 4
  for (int kq = 0; kq < 192; ++kq) {
    float4 bv = *(const float4*)(fj + 4 * kq);
    float4 av = *(const float4*)(a + 4 * kq);
    float b0 = bv.x / nj, b1 = bv.y / nj, b2 = bv.z / nj, b3 = bv.w / nj;
    acc += (double)av.x * (double)b0;
    acc += (double)av.y * (double)b1;
    acc += (double)av.z * (double)b2;
    acc += (double)av.w * (double)b3;
  }
  const float s = (float)acc;   // fl32(truth)

  svals[row][c] = s;
  sidx[row][c]  = j;
  __syncthreads();

  // rank among the 32 candidates: descending by f32 value,
  // exact f32 ties broken HIGHER index first
  int rank = 0;
  for (int k = 0; k < MCAND; ++k) {
    float vk = svals[row][k]; int jk = sidx[row][k];
    rank += (vk > s || (vk == s && jk > j)) ? 1 : 0;
  }
  if (rank < KNN) knnf[(size_t)ig * KNN + rank] = (float)j;
  ssorted[row][rank] = s;
  __syncthreads();

  // numpy pairwise mean over the 20 sorted-desc f32 values
  if (c == 0) {
    float rr[8];
#pragma unroll
    for (int q = 0; q < 8; ++q) rr[q] = ssorted[row][q];
#pragma unroll
    for (int q = 0; q < 8; ++q) rr[q] = rr[q] + ssorted[row][8 + q];
    float res = ((rr[0] + rr[1]) + (rr[2] + rr[3])) + ((rr[4] + rr[5]) + (rr[6] + rr[7]));
    res = res + ssorted[row][16];
    res = res + ssorted[row][17];
    res = res + ssorted[row][18];
    res = res + ssorted[row][19];
    dens[ig] = res / 20.0f;
  }
}

// ---------------------------------------------------------------------------
// peak_mask[i] = all(dens[i] > dens[knn[i][k]])  (f32 comparisons)
// ---------------------------------------------------------------------------
__global__ __launch_bounds__(256) void peak_kernel(const float* __restrict__ dens,
    const float* __restrict__ knnf, float* __restrict__ mask) {
  int i = blockIdx.x * 256 + threadIdx.x;
  if (i >= N_FEAT) return;
  float di = dens[i];
  int ok = 1;
#pragma unroll
  for (int k = 0; k < KNN; ++k) {
    int j = (int)knnf[(size_t)i * KNN + k];
    ok &= (di > dens[j]) ? 1 : 0;
  }
  mask[i] = ok ? 1.0f : 0.0f;
}

// ---------------------------------------------------------------------------
// preds = softmax(hn @ pn^T / tau) @ one_hot(labels)   (unchanged, passing)
// ---------------------------------------------------------------------------
__global__ __launch_bounds__(256) void preds_kernel(const float* __restrict__ H,
    const float* __restrict__ Pk, const int* __restrict__ labels,
    const float* __restrict__ rnh, const float* __restrict__ rnp,
    float* __restrict__ outp) {
  __shared__ __align__(16) float Hs[32][20];
  __shared__ __align__(16) float Ps[32][130];
  __shared__ float accc[16][C_CLS];

  const int t  = threadIdx.x;
  const int hb = blockIdx.x * 16;
  const int tx = t & 63;
  const int ry = t >> 6;
  const int hr  = t >> 4;
  const int hkk = (t & 15) * 2;
  const int pr  = t >> 1;
  const int pkk = (t & 1) * 16;
  const float hrn = rnh[hb + hr];

  for (int i = t; i < 16 * C_CLS; i += 256) ((float*)accc)[i] = 0.f;

  float m[4]    = {-3e38f, -3e38f, -3e38f, -3e38f};
  float ssum[4] = {0.f, 0.f, 0.f, 0.f};
  __syncthreads();

  for (int pt = 0; pt < 16; ++pt) {
    const int pb = pt * 128;
    const float prn = rnp[pb + pr];
    float acc[4][2];
#pragma unroll
    for (int r = 0; r < 4; ++r) { acc[r][0] = 0.f; acc[r][1] = 0.f; }

    for (int kc = 0; kc < 24; ++kc) {
      const int kb = kc * 32;
      __syncthreads();
      {
        float2 v = *(const float2*)(H + (size_t)(hb + hr) * DIM + kb + hkk);
        Hs[hkk][hr]     = v.x * hrn;
        Hs[hkk + 1][hr] = v.y * hrn;
      }
      {
        const float* src = Pk + (size_t)(pb + pr) * DIM + kb + pkk;
        float4 v0 = *(const float4*)(src);
        float4 v1 = *(const float4*)(src + 4);
        float4 v2 = *(const float4*)(src + 8);
        float4 v3 = *(const float4*)(src + 12);
        Ps[pkk +  0][pr] = v0.x * prn;  Ps[pkk +  1][pr] = v0.y * prn;
        Ps[pkk +  2][pr] = v0.z * prn;  Ps[pkk +  3][pr] = v0.w * prn;
        Ps[pkk +  4][pr] = v1.x * prn;  Ps[pkk +  5][pr] = v1.y * prn;
        Ps[pkk +  6][pr] = v1.z * prn;  Ps[pkk +  7][pr] = v1.w * prn;
        Ps[pkk +  8][pr] = v2.x * prn;  Ps[pkk +  9][pr] = v2.y * prn;
        Ps[pkk + 10][pr] = v2.z * prn;  Ps[pkk + 11][pr] = v2.w * prn;
        Ps[pkk + 12][pr] = v3.x * prn;  Ps[pkk + 13][pr] = v3.y * prn;
        Ps[pkk + 14][pr] = v3.z * prn;  Ps[pkk + 15][pr] = v3.w * prn;
      }
      __syncthreads();
#pragma unroll
      for (int k = 0; k < 32; ++k) {
        float4 a = *(const float4*)&Hs[k][4 * ry];
        float2 b = *(const float2*)&Ps[k][2 * tx];
        acc[0][0] += a.x * b.x; acc[0][1] += a.x * b.y;
        acc[1][0] += a.y * b.x; acc[1][1] += a.y * b.y;
        acc[2][0] += a.z * b.x; acc[2][1] += a.z * b.y;
        acc[3][0] += a.w * b.x; acc[3][1] += a.w * b.y;
      }
    }
    const int lab0 = labels[pb + 2 * tx];
    const int lab1 = labels[pb + 2 * tx + 1];
#pragma unroll
    for (int rr = 0; rr < 4; ++rr) {
      float l0 = acc[rr][0] / 0.07f;
      float l1 = acc[rr][1] / 0.07f;
      float tm = fmaxf(l0, l1);
#pragma unroll
      for (int off = 32; off; off >>= 1) tm = fmaxf(tm, __shfl_xor(tm, off));
      float mn = fmaxf(m[rr], tm);
      float sc = expf(m[rr] - mn);
      const int row = 4 * ry + rr;
#pragma unroll
      for (int q = 0; q < 4; ++q) accc[row][tx + 64 * q] *= sc;
      float e0 = expf(l0 - mn);
      float e1 = expf(l1 - mn);
      float es = e0 + e1;
#pragma unroll
      for (int off = 32; off; off >>= 1) es += __shfl_xor(es, off);
      ssum[rr] = ssum[rr] * sc + es;
      m[rr] = mn;
      atomicAdd(&accc[row][lab0], e0);
      atomicAdd(&accc[row][lab1], e1);
    }
  }
#pragma unroll
  for (int rr = 0; rr < 4; ++rr) {
    const int row = 4 * ry + rr;
    float inv = 1.0f / ssum[rr];
#pragma unroll
    for (int q = 0; q < 4; ++q) {
      outp[(size_t)(hb + row) * C_CLS + tx + 64 * q] = accc[row][tx + 64 * q] * inv;
    }
  }
}

// ---------------------------------------------------------------------------
extern "C" void kernel_launch(void* const* d_in, const int* in_sizes, int n_in,
                              void* d_out, int out_size, void* d_ws, size_t ws_size,
                              hipStream_t stream) {
  (void)in_sizes; (void)n_in; (void)out_size; (void)ws_size;
  const float* F      = (const float*)d_in[0];
  const float* H      = (const float*)d_in[1];
  const float* Pk     = (const float*)d_in[2];
  const int*   labels = (const int*)d_in[3];
  float* out = (float*)d_out;

  float* ws   = (float*)d_ws;
  float* nrmF = ws;                    // 8192 (truth-rounded f32 norms)
  float* rnF  = nrmF + N_FEAT;         // 8192 (fast reciprocals)
  float* nrmH = rnF + N_FEAT;          // 4096
  float* rnH  = nrmH + B_H;            // 4096
  float* nrmP = rnH + B_H;             // 2048
  float* rnP  = nrmP + P_PK;           // 2048
  int*   cand = (int*)(rnP + P_PK);    // 8192*32 int

  norm64_kernel<<<N_FEAT / 4, 256, 0, stream>>>(F, nrmF, rnF, N_FEAT);
  norm64_kernel<<<B_H / 4,  256, 0, stream>>>(H, nrmH, rnH, B_H);
  norm64_kernel<<<P_PK / 4, 256, 0, stream>>>(Pk, nrmP, rnP, P_PK);

  sim_topk_kernel<<<N_FEAT / 32, 512, 0, stream>>>(F, rnF, cand);

  refine_kernel<<<N_FEAT / 8, 256, 0, stream>>>(F, nrmF, cand,
      out + OUT_DENS_OFF, out + OUT_KNN_OFF);

  peak_kernel<<<N_FEAT / 256, 256, 0, stream>>>(out + OUT_DENS_OFF,
      out + OUT_KNN_OFF, out + OUT_MASK_OFF);

  preds_kernel<<<B_H / 16, 256, 0, stream>>>(H, Pk, labels, rnH, rnP, out);
}